// Round 1
// baseline (810.817 us; speedup 1.0000x reference)
//
#include <hip/hip_runtime.h>

// KV cache append: out_k = cat(cached_k, new_k, axis=1), out_v likewise.
// B=4, S=4096, NEW=16, D=4096, fp32. Pure memory-bound copy.
constexpr int B_   = 4;
constexpr int S_   = 4096;
constexpr int NEW_ = 16;
constexpr int D_   = 4096;
constexpr int SN_  = S_ + NEW_;            // 4112 rows per batch in output
constexpr int ROW4 = D_ / 4;               // 1024 float4 per row (power of 2)
constexpr long long HALF4 = (long long)B_ * SN_ * ROW4;  // float4 count per output tensor

__global__ __launch_bounds__(256) void kv_append_kernel(
    const float4* __restrict__ ck, const float4* __restrict__ cv,
    const float4* __restrict__ nk, const float4* __restrict__ nv,
    float4* __restrict__ out)
{
    long long v = (long long)blockIdx.x * blockDim.x + threadIdx.x;  // float4 index into d_out
    if (v >= 2 * HALF4) return;

    const float4* cache = ck;
    const float4* fresh = nk;
    long long rem = v;
    if (rem >= HALF4) { rem -= HALF4; cache = cv; fresh = nv; }

    // rem = (b*SN + s)*ROW4 + d4 ; ROW4 is pow2 -> shifts
    long long row = rem >> 10;        // / ROW4
    int d4 = (int)(rem & (ROW4 - 1)); // % ROW4
    int b  = (int)(row / SN_);        // magic-mul
    int s  = (int)(row - (long long)b * SN_);

    float4 val;
    if (s < S_) {
        val = cache[((long long)b * S_ + s) * ROW4 + d4];
    } else {
        val = fresh[((long long)b * NEW_ + (s - S_)) * ROW4 + d4];
    }
    out[v] = val;
}

extern "C" void kernel_launch(void* const* d_in, const int* in_sizes, int n_in,
                              void* d_out, int out_size, void* d_ws, size_t ws_size,
                              hipStream_t stream) {
    const float4* ck = (const float4*)d_in[0];
    const float4* cv = (const float4*)d_in[1];
    const float4* nk = (const float4*)d_in[2];
    const float4* nv = (const float4*)d_in[3];
    float4* out = (float4*)d_out;

    long long total4 = 2 * HALF4;                       // 33,685,504
    int block = 256;
    long long grid = (total4 + block - 1) / block;      // 131,584 blocks
    kv_append_kernel<<<(int)grid, block, 0, stream>>>(ck, cv, nk, nv, out);
}